// Round 10
// baseline (2148.866 us; speedup 1.0000x reference)
//
#include <hip/hip_runtime.h>
#include <math.h>

#define N   50000
#define E   800000
#define F   128
#define DIM 128
#define NF  4
#define ND  32
#define NL  3
#define NC  10
#define G   256
#define NB  196    // ceil(N/256) scan blocks

__device__ __forceinline__ float sigm(float v) { return 1.0f / (1.0f + __expf(-v)); }

// vl[f][k] = sum_j lin0_W[f][k][j]*att_W[f][j] ; vr likewise with Wr; cc[f] = att_b + b.(Wl+Wr)
__global__ void prep_kernel(const float* __restrict__ lin0_W, const float* __restrict__ lin0_b,
                            const float* __restrict__ att_W, const float* __restrict__ att_b,
                            float* __restrict__ vl, float* __restrict__ vr, float* __restrict__ cc) {
    int t = blockIdx.x * blockDim.x + threadIdx.x;
    if (t < NF * F) {
        int f = t >> 7, k = t & 127;
        const float* W  = lin0_W + (size_t)f * F * DIM + (size_t)k * DIM;
        const float* wl = att_W + f * 2 * DIM;
        const float* wr = wl + DIM;
        float sl = 0.f, sr = 0.f;
        for (int j = 0; j < DIM; ++j) { sl += W[j] * wl[j]; sr += W[j] * wr[j]; }
        vl[t] = sl; vr[t] = sr;
    }
    if (t < NF) {
        const float* b  = lin0_b + t * DIM;
        const float* wl = att_W + t * 2 * DIM;
        const float* wr = wl + DIM;
        float s = att_b[t];
        for (int j = 0; j < DIM; ++j) s += b[j] * (wl[j] + wr[j]);
        cc[t] = s;
    }
}

// lane = node, wave = f. Weights are wave-uniform -> SGPR streamed.
__global__ __launch_bounds__(256) void encode_kernel(
        const float* __restrict__ x, const float* __restrict__ enc_W,
        const float* __restrict__ enc_b,
        const float* __restrict__ vl, const float* __restrict__ vr,
        float* __restrict__ out, float* __restrict__ alr) {
    int tid = threadIdx.x;
    int f = __builtin_amdgcn_readfirstlane(tid >> 6);
    int n = blockIdx.x * 64 + (tid & 63);
    int nc = n < N ? n : N - 1;
    const float* px  = x + (size_t)nc * F;
    const float* wf  = enc_W + (size_t)f * F * ND;
    const float* pvl = vl + f * F;
    const float* pvr = vr + f * F;
    const float* pb  = enc_b + f * ND;
    float acc[32];
    #pragma unroll
    for (int j = 0; j < 32; ++j) acc[j] = pb[j];
    float sl = 0.f, sr = 0.f;
    for (int k4 = 0; k4 < 32; ++k4) {
        float4 xv = *(const float4*)(px + k4 * 4);
        float xs[4] = {xv.x, xv.y, xv.z, xv.w};
        #pragma unroll
        for (int u = 0; u < 4; ++u) {
            int k = k4 * 4 + u;
            float xk = xs[u];
            const float* wrow = wf + k * 32;
            #pragma unroll
            for (int j = 0; j < 32; ++j) acc[j] = fmaf(xk, wrow[j], acc[j]);
            sl = fmaf(xk, pvl[k], sl);
            sr = fmaf(xk, pvr[k], sr);
        }
    }
    if (n < N) {
        float* po = out + (size_t)n * DIM + f * ND;
        #pragma unroll
        for (int q = 0; q < 8; ++q)
            *(float4*)(po + q * 4) = make_float4(acc[4*q], acc[4*q+1], acc[4*q+2], acc[4*q+3]);
        alr[(size_t)n * 8 + f]     = sl;
        alr[(size_t)n * 8 + 4 + f] = sr;
    }
}

// ---------------- CSR build ----------------
__global__ void hist_kernel(const int* __restrict__ ei, int* __restrict__ deg) {
    int e = blockIdx.x * 256 + threadIdx.x;
    if (e < E) atomicAdd(&deg[ei[E + e]], 1);
}

__global__ void scan1_kernel(const int* __restrict__ deg, int* __restrict__ rowp,
                             int* __restrict__ bsum) {
    __shared__ int sh[256];
    int i = blockIdx.x * 256 + threadIdx.x;
    int v = (i < N) ? deg[i] : 0;
    sh[threadIdx.x] = v;
    __syncthreads();
    for (int off = 1; off < 256; off <<= 1) {
        int t = 0;
        if ((int)threadIdx.x >= off) t = sh[threadIdx.x - off];
        __syncthreads();
        sh[threadIdx.x] += t;
        __syncthreads();
    }
    if (i < N) rowp[i] = sh[threadIdx.x] - v;
    if (threadIdx.x == 255) bsum[blockIdx.x] = sh[255];
}

__global__ void scan2_kernel(int* __restrict__ bsum) {
    __shared__ int sh[256];
    int v = ((int)threadIdx.x < NB) ? bsum[threadIdx.x] : 0;
    sh[threadIdx.x] = v;
    __syncthreads();
    for (int off = 1; off < 256; off <<= 1) {
        int t = 0;
        if ((int)threadIdx.x >= off) t = sh[threadIdx.x - off];
        __syncthreads();
        sh[threadIdx.x] += t;
        __syncthreads();
    }
    if ((int)threadIdx.x < NB) bsum[threadIdx.x] = sh[threadIdx.x] - v;
}

__global__ void scan3_kernel(int* __restrict__ rowp, const int* __restrict__ bsum) {
    int i = blockIdx.x * 256 + threadIdx.x;
    if (i < N) rowp[i] += bsum[i >> 8];
}

// fill + attention fused: computes the 4 sigmoids from alr, writes the atts output
// AND the permuted per-edge records (esrc, dstp, attp4) for the fused gather.
__global__ void fill_kernel(const int* __restrict__ ei, const float* __restrict__ alr,
                            const float* __restrict__ cc,
                            const int* __restrict__ rowp, int* __restrict__ cnt,
                            int* __restrict__ esrc, int* __restrict__ dstp,
                            float4* __restrict__ attp4, float* __restrict__ atts) {
    int e = blockIdx.x * 256 + threadIdx.x;
    if (e >= E) return;
    int s = ei[e];
    int d = ei[E + e];
    float4 al = *(const float4*)(alr + (size_t)s * 8);
    float4 ar = *(const float4*)(alr + (size_t)d * 8 + 4);
    float a0 = sigm(6.f * (al.x + ar.x + cc[0]));
    float a1 = sigm(6.f * (al.y + ar.y + cc[1]));
    float a2 = sigm(6.f * (al.z + ar.z + cc[2]));
    float a3 = sigm(6.f * (al.w + ar.w + cc[3]));
    atts[e]                 = a0;
    atts[(size_t)E + e]     = a1;
    atts[2 * (size_t)E + e] = a2;
    atts[3 * (size_t)E + e] = a3;
    int slot = rowp[d] + atomicAdd(&cnt[d], 1);
    esrc[slot] = s;
    dstp[slot] = d;
    attp4[slot] = make_float4(a0, a1, a2, a3);
}

// ---------------- FUSED gather + conv + GRU ----------------
// Block = 1 wave (64 thr) owns 32 nodes of group f = blockIdx.y.
// Phase 1: flat edge-parallel gather over the block's contiguous CSR slot range,
//          2 edges per wave-iteration (half-wave each), LDS float atomics into sA.
// Phase 2: conv (m -> sA) + GRU, frozen round-8 register body.
// Double-buffered state: reads st_cur, writes st_next (no cross-block hazard).
__global__ __launch_bounds__(64, 2) void update_kernel(
        const int* __restrict__ esrc, const int* __restrict__ dstp,
        const float4* __restrict__ attp4, const int* __restrict__ rowp,
        const float* __restrict__ st_cur, float* __restrict__ st_next,
        const float* __restrict__ Wrel, const float* __restrict__ brel,
        const float* __restrict__ Wroot,
        const float* __restrict__ Wih, const float* __restrict__ Whh,
        const float* __restrict__ bih, const float* __restrict__ bhh, int l) {
    __shared__ float sA[32 * 32];   // gathered agg, later m
    __shared__ float sH[32 * 32];   // h slice
    int lane = threadIdx.x;
    int f = blockIdx.y;
    int half = lane >> 5;
    int j = lane & 31;
    int node0 = blockIdx.x * 32;
    // zero sA
    float4 z4 = make_float4(0.f, 0.f, 0.f, 0.f);
    #pragma unroll
    for (int q = 0; q < 4; ++q) *(float4*)&sA[lane * 16 + q * 4] = z4;
    // stage h slice for 32 nodes (clamped)
    for (int i4 = lane; i4 < 256; i4 += 64) {        // 256 float4 = 32 nodes x 32 ch
        int node = i4 >> 3, k4 = i4 & 7;
        int n = node0 + node; int nc = n < N ? n : N - 1;
        *(float4*)&sH[node * 32 + k4 * 4] = *(const float4*)(st_cur + (size_t)nc * DIM + f * ND + k4 * 4);
    }
    __syncthreads();
    // ---- phase 1: gather ----
    {
        int beg = rowp[node0];
        int end = (node0 + 32 >= N) ? E : rowp[node0 + 32];
        int nslots = end - beg;
        const float* af = (const float*)attp4 + f;       // component f, stride 4
        const float* sc = st_cur + f * ND + j;           // payload column j
        int i = half;
        for (; i + 6 < nslots; i += 8) {
            int sl0 = beg + i, sl1 = beg + i + 2, sl2 = beg + i + 4, sl3 = beg + i + 6;
            int s0 = esrc[sl0], s1 = esrc[sl1], s2 = esrc[sl2], s3 = esrc[sl3];
            int d0 = dstp[sl0], d1 = dstp[sl1], d2 = dstp[sl2], d3 = dstp[sl3];
            float a0 = af[(size_t)sl0 * 4], a1 = af[(size_t)sl1 * 4];
            float a2 = af[(size_t)sl2 * 4], a3 = af[(size_t)sl3 * 4];
            float v0 = sc[(size_t)s0 * DIM];
            float v1 = sc[(size_t)s1 * DIM];
            float v2 = sc[(size_t)s2 * DIM];
            float v3 = sc[(size_t)s3 * DIM];
            atomicAdd(&sA[(d0 - node0) * 32 + j], a0 * v0);
            atomicAdd(&sA[(d1 - node0) * 32 + j], a1 * v1);
            atomicAdd(&sA[(d2 - node0) * 32 + j], a2 * v2);
            atomicAdd(&sA[(d3 - node0) * 32 + j], a3 * v3);
        }
        for (; i < nslots; i += 2) {
            int sl = beg + i;
            int s = esrc[sl];
            int d = dstp[sl];
            float a = af[(size_t)sl * 4];
            float v = sc[(size_t)s * DIM];
            atomicAdd(&sA[(d - node0) * 32 + j], a * v);
        }
    }
    // ---- phase 2: conv ----
    const float* wrelg  = Wrel  + (size_t)(f * NL + l) * 1024;
    const float* wrootg = Wroot + (size_t)(f * NL + l) * 1024;
    float wr[32], wo[32];
    #pragma unroll
    for (int k = 0; k < 32; ++k) { wr[k] = wrelg[k * 32 + j]; wo[k] = wrootg[k * 32 + j]; }
    float br = brel[(f * NL + l) * 32 + j];
    __syncthreads();
    for (int step = 0; step < 16; ++step) {
        int node = step * 2 + half;
        float a[32], h[32];
        #pragma unroll
        for (int q = 0; q < 8; ++q) {
            *(float4*)&a[q * 4] = *(const float4*)&sA[node * 32 + q * 4];
            *(float4*)&h[q * 4] = *(const float4*)&sH[node * 32 + q * 4];
        }
        float acc = br;
        #pragma unroll
        for (int k = 0; k < 32; ++k) acc = fmaf(a[k], wr[k], fmaf(h[k], wo[k], acc));
        sA[node * 32 + j] = fmaxf(acc, 0.f);      // safe: this step already read node's row
    }
    __syncthreads();
    // ---- phase 2: GRU ----
    const float* wihg = Wih + (size_t)f * 3072;
    const float* whhg = Whh + (size_t)f * 3072;
    float wir[32], wiz[32], win[32], whr[32], whz[32], whn[32];
    #pragma unroll
    for (int q = 0; q < 8; ++q) {
        *(float4*)&wir[q * 4] = *(const float4*)&wihg[(j)      * 32 + q * 4];
        *(float4*)&wiz[q * 4] = *(const float4*)&wihg[(32 + j) * 32 + q * 4];
        *(float4*)&win[q * 4] = *(const float4*)&wihg[(64 + j) * 32 + q * 4];
        *(float4*)&whr[q * 4] = *(const float4*)&whhg[(j)      * 32 + q * 4];
        *(float4*)&whz[q * 4] = *(const float4*)&whhg[(32 + j) * 32 + q * 4];
        *(float4*)&whn[q * 4] = *(const float4*)&whhg[(64 + j) * 32 + q * 4];
    }
    float bi_r = bih[f * 96 + j] + bhh[f * 96 + j];
    float bi_z = bih[f * 96 + 32 + j] + bhh[f * 96 + 32 + j];
    float bi_n = bih[f * 96 + 64 + j];
    float bh_n = bhh[f * 96 + 64 + j];
    for (int step = 0; step < 16; ++step) {
        int node = step * 2 + half;
        int n = node0 + node;
        float racc = bi_r, zacc = bi_z, nacc = bi_n, hnacc = bh_n;
        #pragma unroll
        for (int c = 0; c < 2; ++c) {               // k chunks of 16 (reg pressure)
            float mv[16], hv[16];
            #pragma unroll
            for (int q = 0; q < 4; ++q) {
                *(float4*)&mv[q * 4] = *(const float4*)&sA[node * 32 + c * 16 + q * 4];
                *(float4*)&hv[q * 4] = *(const float4*)&sH[node * 32 + c * 16 + q * 4];
            }
            #pragma unroll
            for (int k = 0; k < 16; ++k) {
                int kk = c * 16 + k;
                racc  = fmaf(mv[k], wir[kk], fmaf(hv[k], whr[kk], racc));
                zacc  = fmaf(mv[k], wiz[kk], fmaf(hv[k], whz[kk], zacc));
                nacc  = fmaf(mv[k], win[kk], nacc);
                hnacc = fmaf(hv[k], whn[kk], hnacc);
            }
        }
        float r  = sigm(racc);
        float z  = sigm(zacc);
        float nn = 2.f * sigm(2.f * (nacc + r * hnacc)) - 1.f;   // tanh
        float hj = sH[node * 32 + j];
        float res = (1.f - z) * nn + z * hj;
        if (n < N) st_next[(size_t)n * DIM + f * ND + j] = res;
    }
}

// ---------------- pooling ----------------
__global__ void ghist_kernel(const int* __restrict__ batch, int* __restrict__ gcnt) {
    int n = blockIdx.x * 256 + threadIdx.x;
    if (n < N) atomicAdd(&gcnt[batch[n]], 1);
}

__global__ void gscan_kernel(const int* __restrict__ gcnt, int* __restrict__ goff) {
    __shared__ int sh[256];
    int v = gcnt[threadIdx.x];
    sh[threadIdx.x] = v;
    __syncthreads();
    for (int off = 1; off < 256; off <<= 1) {
        int t = 0;
        if ((int)threadIdx.x >= off) t = sh[threadIdx.x - off];
        __syncthreads();
        sh[threadIdx.x] += t;
        __syncthreads();
    }
    goff[threadIdx.x] = sh[threadIdx.x] - v;
}

__global__ void pool_kernel(const float* __restrict__ st, const int* __restrict__ goff,
                            const int* __restrict__ gcnt, float* __restrict__ pooled,
                            float* __restrict__ outsout) {
    __shared__ float acc2[128];
    int g = blockIdx.x;
    int c = threadIdx.x & 127;
    int half = threadIdx.x >> 7;
    int beg = goff[g], cnt = gcnt[g];
    float acc = 0.f;
    for (int i = half; i < cnt; i += 2) acc += st[(size_t)(beg + i) * DIM + c];
    if (half == 1) acc2[c] = acc;
    __syncthreads();
    if (half == 0) {
        float tot = acc + acc2[c];
        float val = tot / fmaxf((float)cnt, 1.0f);
        pooled[g * DIM + c] = val;
        int f = c >> 5, d = c & 31;
        outsout[((size_t)f * G + g) * ND + d] = val;
    }
}

__global__ void mlp_kernel(const float* __restrict__ pooled,
                           const float* __restrict__ fc1_W, const float* __restrict__ fc1_b,
                           const float* __restrict__ fc2_W, const float* __restrict__ fc2_b,
                           float* __restrict__ pred) {
    __shared__ float row[DIM], hid[DIM];
    int g = blockIdx.x, c = threadIdx.x;
    row[c] = pooled[(size_t)g * DIM + c];
    __syncthreads();
    float acc = fc1_b[c];
    #pragma unroll 8
    for (int k = 0; k < DIM; ++k) acc += row[k] * fc1_W[k * DIM + c];
    hid[c] = fmaxf(acc, 0.f);
    __syncthreads();
    if (c < NC) {
        float p = fc2_b[c];
        for (int k = 0; k < DIM; ++k) p += hid[k] * fc2_W[k * NC + c];
        pred[(size_t)g * NC + c] = p;
    }
}

extern "C" void kernel_launch(void* const* d_in, const int* in_sizes, int n_in,
                              void* d_out, int out_size, void* d_ws, size_t ws_size,
                              hipStream_t stream) {
    const float* x         = (const float*)d_in[0];
    const int*   ei        = (const int*)  d_in[1];
    const int*   batch     = (const int*)  d_in[2];
    const float* lin0_W    = (const float*)d_in[3];
    const float* lin0_b    = (const float*)d_in[4];
    const float* att_W     = (const float*)d_in[5];
    const float* att_b     = (const float*)d_in[6];
    const float* enc_W     = (const float*)d_in[7];
    const float* enc_b     = (const float*)d_in[8];
    const float* conv_Wrel = (const float*)d_in[9];
    const float* conv_brel = (const float*)d_in[10];
    const float* conv_Wroot= (const float*)d_in[11];
    const float* gru_Wih   = (const float*)d_in[12];
    const float* gru_Whh   = (const float*)d_in[13];
    const float* gru_bih   = (const float*)d_in[14];
    const float* gru_bhh   = (const float*)d_in[15];
    const float* fc1_W     = (const float*)d_in[16];
    const float* fc1_b     = (const float*)d_in[17];
    const float* fc2_W     = (const float*)d_in[18];
    const float* fc2_b     = (const float*)d_in[19];

    float* outp    = (float*)d_out;
    float* pred    = outp;                       // G*NC
    float* atts    = outp + G * NC;              // NF*E
    float* outsout = atts + (size_t)NF * E;      // NF*G*ND

    float* fp     = (float*)d_ws;
    float* st0    = fp;                   fp += (size_t)N * DIM;
    float* st1    = fp;                   fp += (size_t)N * DIM;
    float* alr    = fp;                   fp += (size_t)N * 8;
    float* vl     = fp;                   fp += NF * F;
    float* vr     = fp;                   fp += NF * F;
    float* cc     = fp;                   fp += 4;
    float* pooled = fp;                   fp += G * DIM;
    float4* attp4 = (float4*)fp;          fp += (size_t)NF * E;
    int* ip    = (int*)fp;
    int* deg   = ip;                      ip += N;
    int* cnt   = ip;                      ip += N;   // deg & cnt adjacent -> one memset
    int* rowp  = ip;                      ip += N;
    int* bsum  = ip;                      ip += 256;
    int* gcnt  = ip;                      ip += G;
    int* goff  = ip;                      ip += G;
    int* esrc  = ip;                      ip += E;
    int* dstp  = ip;                      ip += E;

    hipMemsetAsync(deg, 0, (size_t)(2 * N) * sizeof(int), stream);
    hipMemsetAsync(gcnt, 0, (size_t)G * sizeof(int), stream);

    prep_kernel<<<2, 256, 0, stream>>>(lin0_W, lin0_b, att_W, att_b, vl, vr, cc);
    encode_kernel<<<(N + 63) / 64, 256, 0, stream>>>(x, enc_W, enc_b, vl, vr, st0, alr);

    // CSR build (once; reused by all 3 layers); attention fused into fill
    hist_kernel<<<(E + 255) / 256, 256, 0, stream>>>(ei, deg);
    scan1_kernel<<<NB, 256, 0, stream>>>(deg, rowp, bsum);
    scan2_kernel<<<1, 256, 0, stream>>>(bsum);
    scan3_kernel<<<NB, 256, 0, stream>>>(rowp, bsum);
    fill_kernel<<<(E + 255) / 256, 256, 0, stream>>>(ei, alr, cc, rowp, cnt, esrc, dstp, attp4, atts);

    float* stb[2] = {st0, st1};
    for (int l = 0; l < NL; ++l) {
        dim3 gupd((N + 31) / 32, NF);
        update_kernel<<<gupd, 64, 0, stream>>>(esrc, dstp, attp4, rowp,
                                               stb[l & 1], stb[(l + 1) & 1],
                                               conv_Wrel, conv_brel, conv_Wroot,
                                               gru_Wih, gru_Whh, gru_bih, gru_bhh, l);
    }

    ghist_kernel<<<(N + 255) / 256, 256, 0, stream>>>(batch, gcnt);
    gscan_kernel<<<1, 256, 0, stream>>>(gcnt, goff);
    pool_kernel<<<G, 256, 0, stream>>>(st1, goff, gcnt, pooled, outsout);
    mlp_kernel<<<G, DIM, 0, stream>>>(pooled, fc1_W, fc1_b, fc2_W, fc2_b, pred);
}

// Round 11
// 833.575 us; speedup vs baseline: 2.5779x; 2.5779x over previous
//
#include <hip/hip_runtime.h>
#include <math.h>

#define N   50000
#define E   800000
#define F   128
#define DIM 128
#define NF  4
#define ND  32
#define NL  3
#define NC  10
#define G   256
#define NB  196    // ceil(N/256) scan blocks

__device__ __forceinline__ float sigm(float v) { return 1.0f / (1.0f + __expf(-v)); }

// vl[f][k] = sum_j lin0_W[f][k][j]*att_W[f][j] ; vr likewise with Wr; cc[f] = att_b + b.(Wl+Wr)
__global__ void prep_kernel(const float* __restrict__ lin0_W, const float* __restrict__ lin0_b,
                            const float* __restrict__ att_W, const float* __restrict__ att_b,
                            float* __restrict__ vl, float* __restrict__ vr, float* __restrict__ cc) {
    int t = blockIdx.x * blockDim.x + threadIdx.x;
    if (t < NF * F) {
        int f = t >> 7, k = t & 127;
        const float* W  = lin0_W + (size_t)f * F * DIM + (size_t)k * DIM;
        const float* wl = att_W + f * 2 * DIM;
        const float* wr = wl + DIM;
        float sl = 0.f, sr = 0.f;
        for (int j = 0; j < DIM; ++j) { sl += W[j] * wl[j]; sr += W[j] * wr[j]; }
        vl[t] = sl; vr[t] = sr;
    }
    if (t < NF) {
        const float* b  = lin0_b + t * DIM;
        const float* wl = att_W + t * 2 * DIM;
        const float* wr = wl + DIM;
        float s = att_b[t];
        for (int j = 0; j < DIM; ++j) s += b[j] * (wl[j] + wr[j]);
        cc[t] = s;
    }
}

// lane = node, wave = f. Weights are wave-uniform -> SGPR streamed.
__global__ __launch_bounds__(256) void encode_kernel(
        const float* __restrict__ x, const float* __restrict__ enc_W,
        const float* __restrict__ enc_b,
        const float* __restrict__ vl, const float* __restrict__ vr,
        float* __restrict__ out, float* __restrict__ alr) {
    int tid = threadIdx.x;
    int f = __builtin_amdgcn_readfirstlane(tid >> 6);
    int n = blockIdx.x * 64 + (tid & 63);
    int nc = n < N ? n : N - 1;
    const float* px  = x + (size_t)nc * F;
    const float* wf  = enc_W + (size_t)f * F * ND;
    const float* pvl = vl + f * F;
    const float* pvr = vr + f * F;
    const float* pb  = enc_b + f * ND;
    float acc[32];
    #pragma unroll
    for (int j = 0; j < 32; ++j) acc[j] = pb[j];
    float sl = 0.f, sr = 0.f;
    for (int k4 = 0; k4 < 32; ++k4) {
        float4 xv = *(const float4*)(px + k4 * 4);
        float xs[4] = {xv.x, xv.y, xv.z, xv.w};
        #pragma unroll
        for (int u = 0; u < 4; ++u) {
            int k = k4 * 4 + u;
            float xk = xs[u];
            const float* wrow = wf + k * 32;
            #pragma unroll
            for (int j = 0; j < 32; ++j) acc[j] = fmaf(xk, wrow[j], acc[j]);
            sl = fmaf(xk, pvl[k], sl);
            sr = fmaf(xk, pvr[k], sr);
        }
    }
    if (n < N) {
        float* po = out + (size_t)n * DIM + f * ND;
        #pragma unroll
        for (int q = 0; q < 8; ++q)
            *(float4*)(po + q * 4) = make_float4(acc[4*q], acc[4*q+1], acc[4*q+2], acc[4*q+3]);
        alr[(size_t)n * 8 + f]     = sl;
        alr[(size_t)n * 8 + 4 + f] = sr;
    }
}

// ---------------- CSR build ----------------
__global__ void hist_kernel(const int* __restrict__ ei, int* __restrict__ deg) {
    int e = blockIdx.x * 256 + threadIdx.x;
    if (e < E) atomicAdd(&deg[ei[E + e]], 1);
}

__global__ void scan1_kernel(const int* __restrict__ deg, int* __restrict__ rowp,
                             int* __restrict__ bsum) {
    __shared__ int sh[256];
    int i = blockIdx.x * 256 + threadIdx.x;
    int v = (i < N) ? deg[i] : 0;
    sh[threadIdx.x] = v;
    __syncthreads();
    for (int off = 1; off < 256; off <<= 1) {
        int t = 0;
        if ((int)threadIdx.x >= off) t = sh[threadIdx.x - off];
        __syncthreads();
        sh[threadIdx.x] += t;
        __syncthreads();
    }
    if (i < N) rowp[i] = sh[threadIdx.x] - v;
    if (threadIdx.x == 255) bsum[blockIdx.x] = sh[255];
}

__global__ void scan2_kernel(int* __restrict__ bsum) {
    __shared__ int sh[256];
    int v = ((int)threadIdx.x < NB) ? bsum[threadIdx.x] : 0;
    sh[threadIdx.x] = v;
    __syncthreads();
    for (int off = 1; off < 256; off <<= 1) {
        int t = 0;
        if ((int)threadIdx.x >= off) t = sh[threadIdx.x - off];
        __syncthreads();
        sh[threadIdx.x] += t;
        __syncthreads();
    }
    if ((int)threadIdx.x < NB) bsum[threadIdx.x] = sh[threadIdx.x] - v;
}

__global__ void scan3_kernel(int* __restrict__ rowp, const int* __restrict__ bsum) {
    int i = blockIdx.x * 256 + threadIdx.x;
    if (i < N) rowp[i] += bsum[i >> 8];
}

// fill + attention fused: computes the 4 sigmoids from alr, writes the atts output
// (coalesced by e) AND the permuted per-edge record (esrc, attp4) for the gather.
__global__ void fill_kernel(const int* __restrict__ ei, const float* __restrict__ alr,
                            const float* __restrict__ cc,
                            const int* __restrict__ rowp, int* __restrict__ cnt,
                            int* __restrict__ esrc, float4* __restrict__ attp4,
                            float* __restrict__ atts) {
    int e = blockIdx.x * 256 + threadIdx.x;
    if (e >= E) return;
    int s = ei[e];
    int d = ei[E + e];
    float4 al = *(const float4*)(alr + (size_t)s * 8);
    float4 ar = *(const float4*)(alr + (size_t)d * 8 + 4);
    float a0 = sigm(6.f * (al.x + ar.x + cc[0]));
    float a1 = sigm(6.f * (al.y + ar.y + cc[1]));
    float a2 = sigm(6.f * (al.z + ar.z + cc[2]));
    float a3 = sigm(6.f * (al.w + ar.w + cc[3]));
    atts[e]                 = a0;
    atts[(size_t)E + e]     = a1;
    atts[2 * (size_t)E + e] = a2;
    atts[3 * (size_t)E + e] = a3;
    int slot = rowp[d] + atomicAdd(&cnt[d], 1);
    esrc[slot] = s;
    attp4[slot] = make_float4(a0, a1, a2, a3);
}

// ---------------- gather: one wave per node, unroll 8 ----------------
__global__ __launch_bounds__(256) void gather_kernel(
        const int* __restrict__ esrc, const float4* __restrict__ attp4,
        const int* __restrict__ rowp, const int* __restrict__ deg,
        const float* __restrict__ out, float* __restrict__ agg) {
    int gw = (blockIdx.x << 2) | ((int)threadIdx.x >> 6);
    int n = __builtin_amdgcn_readfirstlane(gw);       // wave-uniform node id
    int lane = threadIdx.x & 63;
    int f = lane >> 4;
    int beg = rowp[n];
    int cnt = deg[n];
    const int*   sp = esrc + beg;
    const float* ap = (const float*)(attp4 + beg) + f;   // component f of each record
    const float* ob = out + lane * 2;
    float ax = 0.f, ay = 0.f;
    int i = 0;
    for (; i + 8 <= cnt; i += 8) {
        int s0 = sp[i],     s1 = sp[i + 1], s2 = sp[i + 2], s3 = sp[i + 3];
        int s4 = sp[i + 4], s5 = sp[i + 5], s6 = sp[i + 6], s7 = sp[i + 7];
        float a0 = ap[4*i],      a1 = ap[4*i + 4],  a2 = ap[4*i + 8],  a3 = ap[4*i + 12];
        float a4 = ap[4*i + 16], a5 = ap[4*i + 20], a6 = ap[4*i + 24], a7 = ap[4*i + 28];
        float2 v0 = *(const float2*)(ob + (size_t)s0 * DIM);
        float2 v1 = *(const float2*)(ob + (size_t)s1 * DIM);
        float2 v2 = *(const float2*)(ob + (size_t)s2 * DIM);
        float2 v3 = *(const float2*)(ob + (size_t)s3 * DIM);
        float2 v4 = *(const float2*)(ob + (size_t)s4 * DIM);
        float2 v5 = *(const float2*)(ob + (size_t)s5 * DIM);
        float2 v6 = *(const float2*)(ob + (size_t)s6 * DIM);
        float2 v7 = *(const float2*)(ob + (size_t)s7 * DIM);
        ax += a0 * v0.x + a1 * v1.x + a2 * v2.x + a3 * v3.x
            + a4 * v4.x + a5 * v5.x + a6 * v6.x + a7 * v7.x;
        ay += a0 * v0.y + a1 * v1.y + a2 * v2.y + a3 * v3.y
            + a4 * v4.y + a5 * v5.y + a6 * v6.y + a7 * v7.y;
    }
    for (; i + 4 <= cnt; i += 4) {
        int s0 = sp[i], s1 = sp[i + 1], s2 = sp[i + 2], s3 = sp[i + 3];
        float a0 = ap[4*i], a1 = ap[4*i + 4], a2 = ap[4*i + 8], a3 = ap[4*i + 12];
        float2 v0 = *(const float2*)(ob + (size_t)s0 * DIM);
        float2 v1 = *(const float2*)(ob + (size_t)s1 * DIM);
        float2 v2 = *(const float2*)(ob + (size_t)s2 * DIM);
        float2 v3 = *(const float2*)(ob + (size_t)s3 * DIM);
        ax += a0 * v0.x + a1 * v1.x + a2 * v2.x + a3 * v3.x;
        ay += a0 * v0.y + a1 * v1.y + a2 * v2.y + a3 * v3.y;
    }
    for (; i < cnt; ++i) {
        int s = sp[i];
        float a = ap[4 * i];
        float2 v = *(const float2*)(ob + (size_t)s * DIM);
        ax += a * v.x; ay += a * v.y;
    }
    *(float2*)(agg + (size_t)n * DIM + lane * 2) = make_float2(ax, ay);
}

// ---------------- conv + GRU: lane = output column j, 32 nodes per wave ----------------
// FROZEN round-8 shell (64 thr, __launch_bounds__(64,2), 8KB LDS, 128 VGPR) with
// multi-accumulator inner loops to break the serial FMA dependency chains.
__global__ __launch_bounds__(64, 2) void update_kernel(
        const float* __restrict__ agg, float* __restrict__ out,
        const float* __restrict__ Wrel, const float* __restrict__ brel,
        const float* __restrict__ Wroot,
        const float* __restrict__ Wih, const float* __restrict__ Whh,
        const float* __restrict__ bih, const float* __restrict__ bhh, int l) {
    __shared__ float sA[32 * 32];   // [node][k] agg, later m
    __shared__ float sH[32 * 32];   // [node][k] h
    int lane = threadIdx.x;
    int f = blockIdx.y;
    int half = lane >> 5;
    int j = lane & 31;
    int node0 = blockIdx.x * 32;
    for (int i4 = lane; i4 < 256; i4 += 64) {        // 256 float4 = 32 nodes x 32 ch
        int node = i4 >> 3, k4 = i4 & 7;
        int n = node0 + node; int nc = n < N ? n : N - 1;
        *(float4*)&sA[node * 32 + k4 * 4] = *(const float4*)(agg + (size_t)nc * DIM + f * ND + k4 * 4);
        *(float4*)&sH[node * 32 + k4 * 4] = *(const float4*)(out + (size_t)nc * DIM + f * ND + k4 * 4);
    }
    const float* wrelg  = Wrel  + (size_t)(f * NL + l) * 1024;
    const float* wrootg = Wroot + (size_t)(f * NL + l) * 1024;
    float wr[32], wo[32];
    #pragma unroll
    for (int k = 0; k < 32; ++k) { wr[k] = wrelg[k * 32 + j]; wo[k] = wrootg[k * 32 + j]; }
    float br = brel[(f * NL + l) * 32 + j];
    __syncthreads();
    for (int step = 0; step < 16; ++step) {
        int node = step * 2 + half;
        float a[32], h[32];
        #pragma unroll
        for (int q = 0; q < 8; ++q) {
            *(float4*)&a[q * 4] = *(const float4*)&sA[node * 32 + q * 4];
            *(float4*)&h[q * 4] = *(const float4*)&sH[node * 32 + q * 4];
        }
        // 4 independent partial accumulators: break the 64-deep FMA chain
        float c0 = br, c1 = 0.f, c2 = 0.f, c3 = 0.f;
        #pragma unroll
        for (int k = 0; k < 32; k += 4) {
            c0 = fmaf(a[k],     wr[k],     fmaf(h[k],     wo[k],     c0));
            c1 = fmaf(a[k + 1], wr[k + 1], fmaf(h[k + 1], wo[k + 1], c1));
            c2 = fmaf(a[k + 2], wr[k + 2], fmaf(h[k + 2], wo[k + 2], c2));
            c3 = fmaf(a[k + 3], wr[k + 3], fmaf(h[k + 3], wo[k + 3], c3));
        }
        float acc = (c0 + c1) + (c2 + c3);
        sA[node * 32 + j] = fmaxf(acc, 0.f);      // safe: this step already read node's row
    }
    __syncthreads();
    const float* wihg = Wih + (size_t)f * 3072;
    const float* whhg = Whh + (size_t)f * 3072;
    float wir[32], wiz[32], win[32], whr[32], whz[32], whn[32];
    #pragma unroll
    for (int q = 0; q < 8; ++q) {
        *(float4*)&wir[q * 4] = *(const float4*)&wihg[(j)      * 32 + q * 4];
        *(float4*)&wiz[q * 4] = *(const float4*)&wihg[(32 + j) * 32 + q * 4];
        *(float4*)&win[q * 4] = *(const float4*)&wihg[(64 + j) * 32 + q * 4];
        *(float4*)&whr[q * 4] = *(const float4*)&whhg[(j)      * 32 + q * 4];
        *(float4*)&whz[q * 4] = *(const float4*)&whhg[(32 + j) * 32 + q * 4];
        *(float4*)&whn[q * 4] = *(const float4*)&whhg[(64 + j) * 32 + q * 4];
    }
    float bi_r = bih[f * 96 + j] + bhh[f * 96 + j];
    float bi_z = bih[f * 96 + 32 + j] + bhh[f * 96 + 32 + j];
    float bi_n = bih[f * 96 + 64 + j];
    float bh_n = bhh[f * 96 + 64 + j];
    for (int step = 0; step < 16; ++step) {
        int node = step * 2 + half;
        int n = node0 + node;
        // 8 independent chains (m/h split per gate) instead of 4 nested ones
        float rm = bi_r, rh = 0.f, zm = bi_z, zh = 0.f, nacc = bi_n, hnacc = bh_n;
        #pragma unroll
        for (int c = 0; c < 2; ++c) {               // k chunks of 16 (reg pressure)
            float mv[16], hv[16];
            #pragma unroll
            for (int q = 0; q < 4; ++q) {
                *(float4*)&mv[q * 4] = *(const float4*)&sA[node * 32 + c * 16 + q * 4];
                *(float4*)&hv[q * 4] = *(const float4*)&sH[node * 32 + c * 16 + q * 4];
            }
            #pragma unroll
            for (int k = 0; k < 16; ++k) {
                int kk = c * 16 + k;
                rm    = fmaf(mv[k], wir[kk], rm);
                rh    = fmaf(hv[k], whr[kk], rh);
                zm    = fmaf(mv[k], wiz[kk], zm);
                zh    = fmaf(hv[k], whz[kk], zh);
                nacc  = fmaf(mv[k], win[kk], nacc);
                hnacc = fmaf(hv[k], whn[kk], hnacc);
            }
        }
        float r  = sigm(rm + rh);
        float z  = sigm(zm + zh);
        float nn = 2.f * sigm(2.f * (nacc + r * hnacc)) - 1.f;   // tanh
        float hj = sH[node * 32 + j];
        float res = (1.f - z) * nn + z * hj;
        if (n < N) out[(size_t)n * DIM + f * ND + j] = res;
    }
}

// ---------------- pooling ----------------
__global__ void ghist_kernel(const int* __restrict__ batch, int* __restrict__ gcnt) {
    int n = blockIdx.x * 256 + threadIdx.x;
    if (n < N) atomicAdd(&gcnt[batch[n]], 1);
}

__global__ void gscan_kernel(const int* __restrict__ gcnt, int* __restrict__ goff) {
    __shared__ int sh[256];
    int v = gcnt[threadIdx.x];
    sh[threadIdx.x] = v;
    __syncthreads();
    for (int off = 1; off < 256; off <<= 1) {
        int t = 0;
        if ((int)threadIdx.x >= off) t = sh[threadIdx.x - off];
        __syncthreads();
        sh[threadIdx.x] += t;
        __syncthreads();
    }
    goff[threadIdx.x] = sh[threadIdx.x] - v;
}

__global__ void pool_kernel(const float* __restrict__ st, const int* __restrict__ goff,
                            const int* __restrict__ gcnt, float* __restrict__ pooled,
                            float* __restrict__ outsout) {
    __shared__ float acc2[128];
    int g = blockIdx.x;
    int c = threadIdx.x & 127;
    int half = threadIdx.x >> 7;
    int beg = goff[g], cnt = gcnt[g];
    float acc = 0.f;
    for (int i = half; i < cnt; i += 2) acc += st[(size_t)(beg + i) * DIM + c];
    if (half == 1) acc2[c] = acc;
    __syncthreads();
    if (half == 0) {
        float tot = acc + acc2[c];
        float val = tot / fmaxf((float)cnt, 1.0f);
        pooled[g * DIM + c] = val;
        int f = c >> 5, d = c & 31;
        outsout[((size_t)f * G + g) * ND + d] = val;
    }
}

__global__ void mlp_kernel(const float* __restrict__ pooled,
                           const float* __restrict__ fc1_W, const float* __restrict__ fc1_b,
                           const float* __restrict__ fc2_W, const float* __restrict__ fc2_b,
                           float* __restrict__ pred) {
    __shared__ float row[DIM], hid[DIM];
    int g = blockIdx.x, c = threadIdx.x;
    row[c] = pooled[(size_t)g * DIM + c];
    __syncthreads();
    float acc = fc1_b[c];
    #pragma unroll 8
    for (int k = 0; k < DIM; ++k) acc += row[k] * fc1_W[k * DIM + c];
    hid[c] = fmaxf(acc, 0.f);
    __syncthreads();
    if (c < NC) {
        float p = fc2_b[c];
        for (int k = 0; k < DIM; ++k) p += hid[k] * fc2_W[k * NC + c];
        pred[(size_t)g * NC + c] = p;
    }
}

extern "C" void kernel_launch(void* const* d_in, const int* in_sizes, int n_in,
                              void* d_out, int out_size, void* d_ws, size_t ws_size,
                              hipStream_t stream) {
    const float* x         = (const float*)d_in[0];
    const int*   ei        = (const int*)  d_in[1];
    const int*   batch     = (const int*)  d_in[2];
    const float* lin0_W    = (const float*)d_in[3];
    const float* lin0_b    = (const float*)d_in[4];
    const float* att_W     = (const float*)d_in[5];
    const float* att_b     = (const float*)d_in[6];
    const float* enc_W     = (const float*)d_in[7];
    const float* enc_b     = (const float*)d_in[8];
    const float* conv_Wrel = (const float*)d_in[9];
    const float* conv_brel = (const float*)d_in[10];
    const float* conv_Wroot= (const float*)d_in[11];
    const float* gru_Wih   = (const float*)d_in[12];
    const float* gru_Whh   = (const float*)d_in[13];
    const float* gru_bih   = (const float*)d_in[14];
    const float* gru_bhh   = (const float*)d_in[15];
    const float* fc1_W     = (const float*)d_in[16];
    const float* fc1_b     = (const float*)d_in[17];
    const float* fc2_W     = (const float*)d_in[18];
    const float* fc2_b     = (const float*)d_in[19];

    float* outp    = (float*)d_out;
    float* pred    = outp;                       // G*NC
    float* atts    = outp + G * NC;              // NF*E
    float* outsout = atts + (size_t)NF * E;      // NF*G*ND

    float* fp     = (float*)d_ws;
    float* st     = fp;                   fp += (size_t)N * DIM;
    float* agg    = fp;                   fp += (size_t)N * DIM;
    float* alr    = fp;                   fp += (size_t)N * 8;
    float* vl     = fp;                   fp += NF * F;
    float* vr     = fp;                   fp += NF * F;
    float* cc     = fp;                   fp += 4;
    float* pooled = fp;                   fp += G * DIM;
    float4* attp4 = (float4*)fp;          fp += (size_t)NF * E;
    int* ip    = (int*)fp;
    int* deg   = ip;                      ip += N;
    int* cnt   = ip;                      ip += N;   // deg & cnt adjacent -> one memset
    int* rowp  = ip;                      ip += N;
    int* bsum  = ip;                      ip += 256;
    int* gcnt  = ip;                      ip += G;
    int* goff  = ip;                      ip += G;
    int* esrc  = ip;                      ip += E;

    hipMemsetAsync(deg, 0, (size_t)(2 * N) * sizeof(int), stream);
    hipMemsetAsync(gcnt, 0, (size_t)G * sizeof(int), stream);

    prep_kernel<<<2, 256, 0, stream>>>(lin0_W, lin0_b, att_W, att_b, vl, vr, cc);
    encode_kernel<<<(N + 63) / 64, 256, 0, stream>>>(x, enc_W, enc_b, vl, vr, st, alr);

    // CSR build (once; reused by all 3 layers); attention fused into fill
    hist_kernel<<<(E + 255) / 256, 256, 0, stream>>>(ei, deg);
    scan1_kernel<<<NB, 256, 0, stream>>>(deg, rowp, bsum);
    scan2_kernel<<<1, 256, 0, stream>>>(bsum);
    scan3_kernel<<<NB, 256, 0, stream>>>(rowp, bsum);
    fill_kernel<<<(E + 255) / 256, 256, 0, stream>>>(ei, alr, cc, rowp, cnt, esrc, attp4, atts);

    for (int l = 0; l < NL; ++l) {
        gather_kernel<<<N / 4, 256, 0, stream>>>(esrc, attp4, rowp, deg, st, agg);
        dim3 gupd((N + 31) / 32, NF);
        update_kernel<<<gupd, 64, 0, stream>>>(agg, st, conv_Wrel, conv_brel, conv_Wroot,
                                               gru_Wih, gru_Whh, gru_bih, gru_bhh, l);
    }

    ghist_kernel<<<(N + 255) / 256, 256, 0, stream>>>(batch, gcnt);
    gscan_kernel<<<1, 256, 0, stream>>>(gcnt, goff);
    pool_kernel<<<G, 256, 0, stream>>>(st, goff, gcnt, pooled, outsout);
    mlp_kernel<<<G, DIM, 0, stream>>>(pooled, fc1_W, fc1_b, fc2_W, fc2_b, pred);
}

// Round 12
// 718.396 us; speedup vs baseline: 2.9912x; 1.1603x over previous
//
#include <hip/hip_runtime.h>
#include <math.h>

#define N   50000
#define E   800000
#define F   128
#define DIM 128
#define NF  4
#define ND  32
#define NL  3
#define NC  10
#define G   256
#define NB  196    // ceil(N/256) scan blocks

__device__ __forceinline__ float sigm(float v) { return 1.0f / (1.0f + __expf(-v)); }

__device__ __forceinline__ unsigned int f2bf(float x) {   // RNE round to bf16
    unsigned int u = __float_as_uint(x);
    return (u + 0x7FFFu + ((u >> 16) & 1u)) >> 16;
}

// vl[f][k] = sum_j lin0_W[f][k][j]*att_W[f][j] ; vr likewise with Wr; cc[f] = att_b + b.(Wl+Wr)
__global__ void prep_kernel(const float* __restrict__ lin0_W, const float* __restrict__ lin0_b,
                            const float* __restrict__ att_W, const float* __restrict__ att_b,
                            float* __restrict__ vl, float* __restrict__ vr, float* __restrict__ cc) {
    int t = blockIdx.x * blockDim.x + threadIdx.x;
    if (t < NF * F) {
        int f = t >> 7, k = t & 127;
        const float* W  = lin0_W + (size_t)f * F * DIM + (size_t)k * DIM;
        const float* wl = att_W + f * 2 * DIM;
        const float* wr = wl + DIM;
        float sl = 0.f, sr = 0.f;
        for (int j = 0; j < DIM; ++j) { sl += W[j] * wl[j]; sr += W[j] * wr[j]; }
        vl[t] = sl; vr[t] = sr;
    }
    if (t < NF) {
        const float* b  = lin0_b + t * DIM;
        const float* wl = att_W + t * 2 * DIM;
        const float* wr = wl + DIM;
        float s = att_b[t];
        for (int j = 0; j < DIM; ++j) s += b[j] * (wl[j] + wr[j]);
        cc[t] = s;
    }
}

// lane = node, wave = f. Weights are wave-uniform -> SGPR streamed.
__global__ __launch_bounds__(256) void encode_kernel(
        const float* __restrict__ x, const float* __restrict__ enc_W,
        const float* __restrict__ enc_b,
        const float* __restrict__ vl, const float* __restrict__ vr,
        float* __restrict__ out, unsigned short* __restrict__ st16,
        float* __restrict__ alr) {
    int tid = threadIdx.x;
    int f = __builtin_amdgcn_readfirstlane(tid >> 6);
    int n = blockIdx.x * 64 + (tid & 63);
    int nc = n < N ? n : N - 1;
    const float* px  = x + (size_t)nc * F;
    const float* wf  = enc_W + (size_t)f * F * ND;
    const float* pvl = vl + f * F;
    const float* pvr = vr + f * F;
    const float* pb  = enc_b + f * ND;
    float acc[32];
    #pragma unroll
    for (int j = 0; j < 32; ++j) acc[j] = pb[j];
    float sl = 0.f, sr = 0.f;
    for (int k4 = 0; k4 < 32; ++k4) {
        float4 xv = *(const float4*)(px + k4 * 4);
        float xs[4] = {xv.x, xv.y, xv.z, xv.w};
        #pragma unroll
        for (int u = 0; u < 4; ++u) {
            int k = k4 * 4 + u;
            float xk = xs[u];
            const float* wrow = wf + k * 32;
            #pragma unroll
            for (int j = 0; j < 32; ++j) acc[j] = fmaf(xk, wrow[j], acc[j]);
            sl = fmaf(xk, pvl[k], sl);
            sr = fmaf(xk, pvr[k], sr);
        }
    }
    if (n < N) {
        float* po = out + (size_t)n * DIM + f * ND;
        #pragma unroll
        for (int q = 0; q < 8; ++q)
            *(float4*)(po + q * 4) = make_float4(acc[4*q], acc[4*q+1], acc[4*q+2], acc[4*q+3]);
        unsigned short* p16 = st16 + (size_t)n * DIM + f * ND;
        unsigned int pk[16];
        #pragma unroll
        for (int q = 0; q < 16; ++q)
            pk[q] = f2bf(acc[2*q]) | (f2bf(acc[2*q + 1]) << 16);
        uint4* o16 = (uint4*)p16;
        o16[0] = make_uint4(pk[0], pk[1], pk[2], pk[3]);
        o16[1] = make_uint4(pk[4], pk[5], pk[6], pk[7]);
        o16[2] = make_uint4(pk[8], pk[9], pk[10], pk[11]);
        o16[3] = make_uint4(pk[12], pk[13], pk[14], pk[15]);
        alr[(size_t)n * 8 + f]     = sl;
        alr[(size_t)n * 8 + 4 + f] = sr;
    }
}

// ---------------- CSR build ----------------
__global__ void hist_kernel(const int* __restrict__ ei, int* __restrict__ deg) {
    int e = blockIdx.x * 256 + threadIdx.x;
    if (e < E) atomicAdd(&deg[ei[E + e]], 1);
}

__global__ void scan1_kernel(const int* __restrict__ deg, int* __restrict__ rowp,
                             int* __restrict__ bsum) {
    __shared__ int sh[256];
    int i = blockIdx.x * 256 + threadIdx.x;
    int v = (i < N) ? deg[i] : 0;
    sh[threadIdx.x] = v;
    __syncthreads();
    for (int off = 1; off < 256; off <<= 1) {
        int t = 0;
        if ((int)threadIdx.x >= off) t = sh[threadIdx.x - off];
        __syncthreads();
        sh[threadIdx.x] += t;
        __syncthreads();
    }
    if (i < N) rowp[i] = sh[threadIdx.x] - v;
    if (threadIdx.x == 255) bsum[blockIdx.x] = sh[255];
}

__global__ void scan2_kernel(int* __restrict__ bsum) {
    __shared__ int sh[256];
    int v = ((int)threadIdx.x < NB) ? bsum[threadIdx.x] : 0;
    sh[threadIdx.x] = v;
    __syncthreads();
    for (int off = 1; off < 256; off <<= 1) {
        int t = 0;
        if ((int)threadIdx.x >= off) t = sh[threadIdx.x - off];
        __syncthreads();
        sh[threadIdx.x] += t;
        __syncthreads();
    }
    if ((int)threadIdx.x < NB) bsum[threadIdx.x] = sh[threadIdx.x] - v;
}

__global__ void scan3_kernel(int* __restrict__ rowp, const int* __restrict__ bsum) {
    int i = blockIdx.x * 256 + threadIdx.x;
    if (i < N) rowp[i] += bsum[i >> 8];
}

// fill + attention fused: computes the 4 sigmoids from alr, writes the atts output
// (coalesced by e) AND the permuted per-edge record (esrc, attp4) for the gather.
__global__ void fill_kernel(const int* __restrict__ ei, const float* __restrict__ alr,
                            const float* __restrict__ cc,
                            const int* __restrict__ rowp, int* __restrict__ cnt,
                            int* __restrict__ esrc, float4* __restrict__ attp4,
                            float* __restrict__ atts) {
    int e = blockIdx.x * 256 + threadIdx.x;
    if (e >= E) return;
    int s = ei[e];
    int d = ei[E + e];
    float4 al = *(const float4*)(alr + (size_t)s * 8);
    float4 ar = *(const float4*)(alr + (size_t)d * 8 + 4);
    float a0 = sigm(6.f * (al.x + ar.x + cc[0]));
    float a1 = sigm(6.f * (al.y + ar.y + cc[1]));
    float a2 = sigm(6.f * (al.z + ar.z + cc[2]));
    float a3 = sigm(6.f * (al.w + ar.w + cc[3]));
    atts[e]                 = a0;
    atts[(size_t)E + e]     = a1;
    atts[2 * (size_t)E + e] = a2;
    atts[3 * (size_t)E + e] = a3;
    int slot = rowp[d] + atomicAdd(&cnt[d], 1);
    esrc[slot] = s;
    attp4[slot] = make_float4(a0, a1, a2, a3);
}

// ---------------- gather: one wave per node, unroll 8, bf16 payload ----------------
__global__ __launch_bounds__(256) void gather_kernel(
        const int* __restrict__ esrc, const float4* __restrict__ attp4,
        const int* __restrict__ rowp, const int* __restrict__ deg,
        const unsigned short* __restrict__ st16, float* __restrict__ agg) {
    int gw = (blockIdx.x << 2) | ((int)threadIdx.x >> 6);
    int n = __builtin_amdgcn_readfirstlane(gw);       // wave-uniform node id
    int lane = threadIdx.x & 63;
    int f = lane >> 4;
    int beg = rowp[n];
    int cnt = deg[n];
    const int*   sp = esrc + beg;
    const float* ap = (const float*)(attp4 + beg) + f;   // component f of each record
    const unsigned short* ob = st16 + lane * 2;          // channels 2*lane, 2*lane+1
    float ax = 0.f, ay = 0.f;
    int i = 0;
    for (; i + 8 <= cnt; i += 8) {
        int s0 = sp[i],     s1 = sp[i + 1], s2 = sp[i + 2], s3 = sp[i + 3];
        int s4 = sp[i + 4], s5 = sp[i + 5], s6 = sp[i + 6], s7 = sp[i + 7];
        float a0 = ap[4*i],      a1 = ap[4*i + 4],  a2 = ap[4*i + 8],  a3 = ap[4*i + 12];
        float a4 = ap[4*i + 16], a5 = ap[4*i + 20], a6 = ap[4*i + 24], a7 = ap[4*i + 28];
        unsigned int u0 = *(const unsigned int*)(ob + (size_t)s0 * DIM);
        unsigned int u1 = *(const unsigned int*)(ob + (size_t)s1 * DIM);
        unsigned int u2 = *(const unsigned int*)(ob + (size_t)s2 * DIM);
        unsigned int u3 = *(const unsigned int*)(ob + (size_t)s3 * DIM);
        unsigned int u4 = *(const unsigned int*)(ob + (size_t)s4 * DIM);
        unsigned int u5 = *(const unsigned int*)(ob + (size_t)s5 * DIM);
        unsigned int u6 = *(const unsigned int*)(ob + (size_t)s6 * DIM);
        unsigned int u7 = *(const unsigned int*)(ob + (size_t)s7 * DIM);
        ax += a0 * __uint_as_float(u0 << 16) + a1 * __uint_as_float(u1 << 16)
            + a2 * __uint_as_float(u2 << 16) + a3 * __uint_as_float(u3 << 16)
            + a4 * __uint_as_float(u4 << 16) + a5 * __uint_as_float(u5 << 16)
            + a6 * __uint_as_float(u6 << 16) + a7 * __uint_as_float(u7 << 16);
        ay += a0 * __uint_as_float(u0 & 0xFFFF0000u) + a1 * __uint_as_float(u1 & 0xFFFF0000u)
            + a2 * __uint_as_float(u2 & 0xFFFF0000u) + a3 * __uint_as_float(u3 & 0xFFFF0000u)
            + a4 * __uint_as_float(u4 & 0xFFFF0000u) + a5 * __uint_as_float(u5 & 0xFFFF0000u)
            + a6 * __uint_as_float(u6 & 0xFFFF0000u) + a7 * __uint_as_float(u7 & 0xFFFF0000u);
    }
    for (; i + 4 <= cnt; i += 4) {
        int s0 = sp[i], s1 = sp[i + 1], s2 = sp[i + 2], s3 = sp[i + 3];
        float a0 = ap[4*i], a1 = ap[4*i + 4], a2 = ap[4*i + 8], a3 = ap[4*i + 12];
        unsigned int u0 = *(const unsigned int*)(ob + (size_t)s0 * DIM);
        unsigned int u1 = *(const unsigned int*)(ob + (size_t)s1 * DIM);
        unsigned int u2 = *(const unsigned int*)(ob + (size_t)s2 * DIM);
        unsigned int u3 = *(const unsigned int*)(ob + (size_t)s3 * DIM);
        ax += a0 * __uint_as_float(u0 << 16) + a1 * __uint_as_float(u1 << 16)
            + a2 * __uint_as_float(u2 << 16) + a3 * __uint_as_float(u3 << 16);
        ay += a0 * __uint_as_float(u0 & 0xFFFF0000u) + a1 * __uint_as_float(u1 & 0xFFFF0000u)
            + a2 * __uint_as_float(u2 & 0xFFFF0000u) + a3 * __uint_as_float(u3 & 0xFFFF0000u);
    }
    for (; i < cnt; ++i) {
        int s = sp[i];
        float a = ap[4 * i];
        unsigned int u = *(const unsigned int*)(ob + (size_t)s * DIM);
        ax += a * __uint_as_float(u << 16);
        ay += a * __uint_as_float(u & 0xFFFF0000u);
    }
    *(float2*)(agg + (size_t)n * DIM + lane * 2) = make_float2(ax, ay);
}

// ---------------- conv + GRU: lane = output column j, 32 nodes per wave ----------------
// FROZEN round-9 body (64 thr, __launch_bounds__(64,2), 8KB LDS, 128 VGPR, nested
// fmaf chains — multi-acc variants regressed). Adds the bf16 sidecar store.
__global__ __launch_bounds__(64, 2) void update_kernel(
        const float* __restrict__ agg, float* __restrict__ out,
        unsigned short* __restrict__ st16,
        const float* __restrict__ Wrel, const float* __restrict__ brel,
        const float* __restrict__ Wroot,
        const float* __restrict__ Wih, const float* __restrict__ Whh,
        const float* __restrict__ bih, const float* __restrict__ bhh, int l) {
    __shared__ float sA[32 * 32];   // [node][k] agg, later m
    __shared__ float sH[32 * 32];   // [node][k] h
    int lane = threadIdx.x;
    int f = blockIdx.y;
    int half = lane >> 5;
    int j = lane & 31;
    int node0 = blockIdx.x * 32;
    for (int i4 = lane; i4 < 256; i4 += 64) {        // 256 float4 = 32 nodes x 32 ch
        int node = i4 >> 3, k4 = i4 & 7;
        int n = node0 + node; int nc = n < N ? n : N - 1;
        *(float4*)&sA[node * 32 + k4 * 4] = *(const float4*)(agg + (size_t)nc * DIM + f * ND + k4 * 4);
        *(float4*)&sH[node * 32 + k4 * 4] = *(const float4*)(out + (size_t)nc * DIM + f * ND + k4 * 4);
    }
    const float* wrelg  = Wrel  + (size_t)(f * NL + l) * 1024;
    const float* wrootg = Wroot + (size_t)(f * NL + l) * 1024;
    float wr[32], wo[32];
    #pragma unroll
    for (int k = 0; k < 32; ++k) { wr[k] = wrelg[k * 32 + j]; wo[k] = wrootg[k * 32 + j]; }
    float br = brel[(f * NL + l) * 32 + j];
    __syncthreads();
    for (int step = 0; step < 16; ++step) {
        int node = step * 2 + half;
        float a[32], h[32];
        #pragma unroll
        for (int q = 0; q < 8; ++q) {
            *(float4*)&a[q * 4] = *(const float4*)&sA[node * 32 + q * 4];
            *(float4*)&h[q * 4] = *(const float4*)&sH[node * 32 + q * 4];
        }
        float acc = br;
        #pragma unroll
        for (int k = 0; k < 32; ++k) acc = fmaf(a[k], wr[k], fmaf(h[k], wo[k], acc));
        sA[node * 32 + j] = fmaxf(acc, 0.f);      // safe: this step already read node's row
    }
    __syncthreads();
    const float* wihg = Wih + (size_t)f * 3072;
    const float* whhg = Whh + (size_t)f * 3072;
    float wir[32], wiz[32], win[32], whr[32], whz[32], whn[32];
    #pragma unroll
    for (int q = 0; q < 8; ++q) {
        *(float4*)&wir[q * 4] = *(const float4*)&wihg[(j)      * 32 + q * 4];
        *(float4*)&wiz[q * 4] = *(const float4*)&wihg[(32 + j) * 32 + q * 4];
        *(float4*)&win[q * 4] = *(const float4*)&wihg[(64 + j) * 32 + q * 4];
        *(float4*)&whr[q * 4] = *(const float4*)&whhg[(j)      * 32 + q * 4];
        *(float4*)&whz[q * 4] = *(const float4*)&whhg[(32 + j) * 32 + q * 4];
        *(float4*)&whn[q * 4] = *(const float4*)&whhg[(64 + j) * 32 + q * 4];
    }
    float bi_r = bih[f * 96 + j] + bhh[f * 96 + j];
    float bi_z = bih[f * 96 + 32 + j] + bhh[f * 96 + 32 + j];
    float bi_n = bih[f * 96 + 64 + j];
    float bh_n = bhh[f * 96 + 64 + j];
    for (int step = 0; step < 16; ++step) {
        int node = step * 2 + half;
        int n = node0 + node;
        float racc = bi_r, zacc = bi_z, nacc = bi_n, hnacc = bh_n;
        #pragma unroll
        for (int c = 0; c < 2; ++c) {               // k chunks of 16 (reg pressure)
            float mv[16], hv[16];
            #pragma unroll
            for (int q = 0; q < 4; ++q) {
                *(float4*)&mv[q * 4] = *(const float4*)&sA[node * 32 + c * 16 + q * 4];
                *(float4*)&hv[q * 4] = *(const float4*)&sH[node * 32 + c * 16 + q * 4];
            }
            #pragma unroll
            for (int k = 0; k < 16; ++k) {
                int kk = c * 16 + k;
                racc  = fmaf(hv[k], whr[kk], fmaf(mv[k], wir[kk], racc));
                zacc  = fmaf(hv[k], whz[kk], fmaf(mv[k], wiz[kk], zacc));
                nacc  = fmaf(mv[k], win[kk], nacc);
                hnacc = fmaf(hv[k], whn[kk], hnacc);
            }
        }
        float r  = sigm(racc);
        float z  = sigm(zacc);
        float nn = 2.f * sigm(2.f * (nacc + r * hnacc)) - 1.f;   // tanh
        float hj = sH[node * 32 + j];
        float res = (1.f - z) * nn + z * hj;
        if (n < N) {
            out[(size_t)n * DIM + f * ND + j] = res;
            st16[(size_t)n * DIM + f * ND + j] = (unsigned short)f2bf(res);
        }
    }
}

// ---------------- pooling ----------------
__global__ void ghist_kernel(const int* __restrict__ batch, int* __restrict__ gcnt) {
    int n = blockIdx.x * 256 + threadIdx.x;
    if (n < N) atomicAdd(&gcnt[batch[n]], 1);
}

__global__ void gscan_kernel(const int* __restrict__ gcnt, int* __restrict__ goff) {
    __shared__ int sh[256];
    int v = gcnt[threadIdx.x];
    sh[threadIdx.x] = v;
    __syncthreads();
    for (int off = 1; off < 256; off <<= 1) {
        int t = 0;
        if ((int)threadIdx.x >= off) t = sh[threadIdx.x - off];
        __syncthreads();
        sh[threadIdx.x] += t;
        __syncthreads();
    }
    goff[threadIdx.x] = sh[threadIdx.x] - v;
}

__global__ void pool_kernel(const float* __restrict__ st, const int* __restrict__ goff,
                            const int* __restrict__ gcnt, float* __restrict__ pooled,
                            float* __restrict__ outsout) {
    __shared__ float acc2[128];
    int g = blockIdx.x;
    int c = threadIdx.x & 127;
    int half = threadIdx.x >> 7;
    int beg = goff[g], cnt = gcnt[g];
    float acc = 0.f;
    for (int i = half; i < cnt; i += 2) acc += st[(size_t)(beg + i) * DIM + c];
    if (half == 1) acc2[c] = acc;
    __syncthreads();
    if (half == 0) {
        float tot = acc + acc2[c];
        float val = tot / fmaxf((float)cnt, 1.0f);
        pooled[g * DIM + c] = val;
        int f = c >> 5, d = c & 31;
        outsout[((size_t)f * G + g) * ND + d] = val;
    }
}

__global__ void mlp_kernel(const float* __restrict__ pooled,
                           const float* __restrict__ fc1_W, const float* __restrict__ fc1_b,
                           const float* __restrict__ fc2_W, const float* __restrict__ fc2_b,
                           float* __restrict__ pred) {
    __shared__ float row[DIM], hid[DIM];
    int g = blockIdx.x, c = threadIdx.x;
    row[c] = pooled[(size_t)g * DIM + c];
    __syncthreads();
    float acc = fc1_b[c];
    #pragma unroll 8
    for (int k = 0; k < DIM; ++k) acc += row[k] * fc1_W[k * DIM + c];
    hid[c] = fmaxf(acc, 0.f);
    __syncthreads();
    if (c < NC) {
        float p = fc2_b[c];
        for (int k = 0; k < DIM; ++k) p += hid[k] * fc2_W[k * NC + c];
        pred[(size_t)g * NC + c] = p;
    }
}

extern "C" void kernel_launch(void* const* d_in, const int* in_sizes, int n_in,
                              void* d_out, int out_size, void* d_ws, size_t ws_size,
                              hipStream_t stream) {
    const float* x         = (const float*)d_in[0];
    const int*   ei        = (const int*)  d_in[1];
    const int*   batch     = (const int*)  d_in[2];
    const float* lin0_W    = (const float*)d_in[3];
    const float* lin0_b    = (const float*)d_in[4];
    const float* att_W     = (const float*)d_in[5];
    const float* att_b     = (const float*)d_in[6];
    const float* enc_W     = (const float*)d_in[7];
    const float* enc_b     = (const float*)d_in[8];
    const float* conv_Wrel = (const float*)d_in[9];
    const float* conv_brel = (const float*)d_in[10];
    const float* conv_Wroot= (const float*)d_in[11];
    const float* gru_Wih   = (const float*)d_in[12];
    const float* gru_Whh   = (const float*)d_in[13];
    const float* gru_bih   = (const float*)d_in[14];
    const float* gru_bhh   = (const float*)d_in[15];
    const float* fc1_W     = (const float*)d_in[16];
    const float* fc1_b     = (const float*)d_in[17];
    const float* fc2_W     = (const float*)d_in[18];
    const float* fc2_b     = (const float*)d_in[19];

    float* outp    = (float*)d_out;
    float* pred    = outp;                       // G*NC
    float* atts    = outp + G * NC;              // NF*E
    float* outsout = atts + (size_t)NF * E;      // NF*G*ND

    float* fp     = (float*)d_ws;
    float* st     = fp;                   fp += (size_t)N * DIM;
    float* agg    = fp;                   fp += (size_t)N * DIM;
    unsigned short* st16 = (unsigned short*)fp;  fp += (size_t)N * DIM / 2;
    float* alr    = fp;                   fp += (size_t)N * 8;
    float* vl     = fp;                   fp += NF * F;
    float* vr     = fp;                   fp += NF * F;
    float* cc     = fp;                   fp += 4;
    float* pooled = fp;                   fp += G * DIM;
    float4* attp4 = (float4*)fp;          fp += (size_t)NF * E;
    int* ip    = (int*)fp;
    int* deg   = ip;                      ip += N;
    int* cnt   = ip;                      ip += N;   // deg & cnt adjacent -> one memset
    int* rowp  = ip;                      ip += N;
    int* bsum  = ip;                      ip += 256;
    int* gcnt  = ip;                      ip += G;
    int* goff  = ip;                      ip += G;
    int* esrc  = ip;                      ip += E;

    hipMemsetAsync(deg, 0, (size_t)(2 * N) * sizeof(int), stream);
    hipMemsetAsync(gcnt, 0, (size_t)G * sizeof(int), stream);

    prep_kernel<<<2, 256, 0, stream>>>(lin0_W, lin0_b, att_W, att_b, vl, vr, cc);
    encode_kernel<<<(N + 63) / 64, 256, 0, stream>>>(x, enc_W, enc_b, vl, vr, st, st16, alr);

    // CSR build (once; reused by all 3 layers); attention fused into fill
    hist_kernel<<<(E + 255) / 256, 256, 0, stream>>>(ei, deg);
    scan1_kernel<<<NB, 256, 0, stream>>>(deg, rowp, bsum);
    scan2_kernel<<<1, 256, 0, stream>>>(bsum);
    scan3_kernel<<<NB, 256, 0, stream>>>(rowp, bsum);
    fill_kernel<<<(E + 255) / 256, 256, 0, stream>>>(ei, alr, cc, rowp, cnt, esrc, attp4, atts);

    for (int l = 0; l < NL; ++l) {
        gather_kernel<<<N / 4, 256, 0, stream>>>(esrc, attp4, rowp, deg, st16, agg);
        dim3 gupd((N + 31) / 32, NF);
        update_kernel<<<gupd, 64, 0, stream>>>(agg, st, st16, conv_Wrel, conv_brel, conv_Wroot,
                                               gru_Wih, gru_Whh, gru_bih, gru_bhh, l);
    }

    ghist_kernel<<<(N + 255) / 256, 256, 0, stream>>>(batch, gcnt);
    gscan_kernel<<<1, 256, 0, stream>>>(gcnt, goff);
    pool_kernel<<<G, 256, 0, stream>>>(st, goff, gcnt, pooled, outsout);
    mlp_kernel<<<G, DIM, 0, stream>>>(pooled, fc1_W, fc1_b, fc2_W, fc2_b, pred);
}